// Round 9
// baseline (739.963 us; speedup 1.0000x reference)
//
#include <hip/hip_runtime.h>
#include <hip/hip_fp16.h>
#include <stdint.h>

#define HD   4096
#define MDIM 14336
#define TOKN 64

typedef _Float16 half8 __attribute__((ext_vector_type(8)));
typedef float    f32x4 __attribute__((ext_vector_type(4)));

__constant__ float NF4_TBL[16] = {
    -1.0f, -0.6961928009986877f, -0.5250730514526367f, -0.39491748809814453f,
    -0.28444138169288635f, -0.18477343022823334f, -0.09105003625154495f, 0.0f,
    0.07958029955625534f, 0.16093020141124725f, 0.24611230194568634f,
    0.33791524171829224f, 0.44070982933044434f, 0.5626170039176941f,
    0.8333333134651184f, 1.0f};

__device__ __forceinline__ void lut_fill(uint32_t* lut, int tid) {
  if (tid < 256) {
    __half lo = __float2half(NF4_TBL[tid & 15]);
    __half hi = __float2half(NF4_TBL[tid >> 4]);
    lut[tid] = (uint32_t)__half_as_ushort(lo) |
               ((uint32_t)__half_as_ushort(hi) << 16);
  }
}

__device__ __forceinline__ half8 mk_bfrag(const uint32_t* lut, int4 ca, int4 cb) {
  union { uint32_t u[4]; half8 h; } bu;
  bu.u[0] = lut[ca.x | (ca.y << 4)];
  bu.u[1] = lut[ca.z | (ca.w << 4)];
  bu.u[2] = lut[cb.x | (cb.y << 4)];
  bu.u[3] = lut[cb.z | (cb.w << 4)];
  return bu.h;
}

// Barrier-free per-wave register pipeline.
// crow: per-lane code base  = codes + row*K + sp*kch + q*8
// srow: per-lane scale base = scl + row*(K/64) + sp*nt
// arow: per-lane A base     = act + sp*kch + r15*K + q*8
// astr16 = 16*K (elements). nt % 4 == 0, nt >= 4.
// Code ring depth 4 (use-distance 4 steps hides HBM ~900cy); A ring depth 2 (L2).
__device__ __forceinline__ void nf4_gemm_reg(
    const int* __restrict__ crow, const float* __restrict__ srow,
    const _Float16* __restrict__ arow, int astr16, int nt,
    const uint32_t* lut, f32x4 acc[4])
{
  int4 c00, c10, c20, c30, c01, c11, c21, c31;
  int4 c02, c12, c22, c32, c03, c13, c23, c33;
  float s0, s1, s2, s3;
  half8 a00, a01, a02, a03, a04, a05, a06, a07;
  half8 a10, a11, a12, a13, a14, a15, a16, a17;

#define LOADC(n, t) { int te = ((t) < nt) ? (t) : nt - 1;                \
    const int* p = crow + (size_t)te * 64;                               \
    c0##n = *(const int4*)(p);      c1##n = *(const int4*)(p + 4);       \
    c2##n = *(const int4*)(p + 32); c3##n = *(const int4*)(p + 36);      \
    s##n = srow[te]; }

#define LOADA(n, t) { int te = ((t) < nt) ? (t) : nt - 1;                \
    const _Float16* p = arow + (size_t)te * 64;                          \
    a##n##0 = *(const half8*)(p);                                        \
    a##n##1 = *(const half8*)(p + 32);                                   \
    a##n##2 = *(const half8*)(p + astr16);                               \
    a##n##3 = *(const half8*)(p + astr16 + 32);                          \
    a##n##4 = *(const half8*)(p + 2 * astr16);                           \
    a##n##5 = *(const half8*)(p + 2 * astr16 + 32);                      \
    a##n##6 = *(const half8*)(p + 3 * astr16);                           \
    a##n##7 = *(const half8*)(p + 3 * astr16 + 32); }

#define COMPUTE(n, m) {                                                  \
    _Float16 sh = (_Float16)s##n;                                        \
    half8 sv = {sh, sh, sh, sh, sh, sh, sh, sh};                         \
    half8 bf0 = mk_bfrag(lut, c0##n, c1##n) * sv;                        \
    half8 bf1 = mk_bfrag(lut, c2##n, c3##n) * sv;                        \
    acc[0] = __builtin_amdgcn_mfma_f32_16x16x32_f16(a##m##0, bf0, acc[0], 0, 0, 0); \
    acc[0] = __builtin_amdgcn_mfma_f32_16x16x32_f16(a##m##1, bf1, acc[0], 0, 0, 0); \
    acc[1] = __builtin_amdgcn_mfma_f32_16x16x32_f16(a##m##2, bf0, acc[1], 0, 0, 0); \
    acc[1] = __builtin_amdgcn_mfma_f32_16x16x32_f16(a##m##3, bf1, acc[1], 0, 0, 0); \
    acc[2] = __builtin_amdgcn_mfma_f32_16x16x32_f16(a##m##4, bf0, acc[2], 0, 0, 0); \
    acc[2] = __builtin_amdgcn_mfma_f32_16x16x32_f16(a##m##5, bf1, acc[2], 0, 0, 0); \
    acc[3] = __builtin_amdgcn_mfma_f32_16x16x32_f16(a##m##6, bf0, acc[3], 0, 0, 0); \
    acc[3] = __builtin_amdgcn_mfma_f32_16x16x32_f16(a##m##7, bf1, acc[3], 0, 0, 0); }

  LOADC(0, 0) LOADC(1, 1) LOADC(2, 2) LOADC(3, 3)
  LOADA(0, 0)
  for (int T = 0; T < nt; T += 4) {
    LOADA(1, T + 1)
    COMPUTE(0, 0)
    LOADC(0, T + 4)
    LOADA(0, T + 2)
    COMPUTE(1, 1)
    LOADC(1, T + 5)
    LOADA(1, T + 3)
    COMPUTE(2, 0)
    LOADC(2, T + 6)
    LOADA(0, T + 4)
    COMPUTE(3, 1)
    LOADC(3, T + 7)
  }
#undef LOADC
#undef LOADA
#undef COMPUTE
}

// x fp32 -> fp16
__global__ void k_cvt_x(const float* __restrict__ x, _Float16* __restrict__ xh) {
  int i = blockIdx.x * blockDim.x + threadIdx.x;
  float4 v = ((const float4*)x)[i];
  union { _Float16 h[4]; uint2 u; } o;
  o.h[0] = (_Float16)v.x; o.h[1] = (_Float16)v.y;
  o.h[2] = (_Float16)v.z; o.h[3] = (_Float16)v.w;
  ((uint2*)xh)[i] = o.u;
}

// gate & up GEMM: grid = 448*gsplit; block = 64 out-cols x 64 tokens
__global__ __launch_bounds__(256, 2) void k_gemm_gu(
    const int* __restrict__ gc, const float* __restrict__ gs,
    const int* __restrict__ uc, const float* __restrict__ us,
    const _Float16* __restrict__ xh,
    float* __restrict__ gpart, float* __restrict__ upart, int gsplit)
{
  __shared__ uint32_t lut[256];
  int tid = threadIdx.x;
  lut_fill(lut, tid);
  __syncthreads();

  int bx = blockIdx.x;
  int sp = bx % gsplit;
  int r  = bx / gsplit;
  int mat  = (r >= 224);
  int mblk = mat ? r - 224 : r;
  const int*   codes = mat ? uc : gc;
  const float* scl   = mat ? us : gs;
  float*       outp  = (mat ? upart : gpart) + (size_t)sp * (TOKN * MDIM);

  int kch = HD / gsplit;
  int nt  = kch / 64;
  int mbase = mblk * 64;

  int lane = tid & 63, wid = tid >> 6;
  int r15 = lane & 15, q = lane >> 4;
  int mrow = mbase + wid * 16 + r15;

  const int*      crow = codes + (size_t)mrow * HD + (size_t)sp * kch + q * 8;
  const float*    srow = scl + (size_t)mrow * (HD / 64) + (size_t)sp * nt;
  const _Float16* arow = xh + (size_t)sp * kch + (size_t)r15 * HD + q * 8;

  f32x4 acc[4];
#pragma unroll
  for (int t = 0; t < 4; ++t) acc[t] = (f32x4){0.f, 0.f, 0.f, 0.f};

  nf4_gemm_reg(crow, srow, arow, 16 * HD, nt, lut, acc);

#pragma unroll
  for (int t = 0; t < 4; ++t)
#pragma unroll
    for (int rr = 0; rr < 4; ++rr) {
      int token = t * 16 + 4 * q + rr;          // D: row = 4*(lane>>4)+reg
      outp[(size_t)token * MDIM + mbase + wid * 16 + r15] = acc[t][rr];
    }
}

// fused split-reduce + SwiGLU, fp32 parts -> fp16 h
__global__ void k_reduce_swiglu(const float* __restrict__ gpart,
                                const float* __restrict__ upart,
                                _Float16* __restrict__ h, int gsplit) {
  int i = blockIdx.x * blockDim.x + threadIdx.x;
  float4 g = ((const float4*)gpart)[i];
  float4 u = ((const float4*)upart)[i];
  for (int s = 1; s < gsplit; ++s) {
    float4 gb = ((const float4*)(gpart + (size_t)s * (TOKN * MDIM)))[i];
    float4 ub = ((const float4*)(upart + (size_t)s * (TOKN * MDIM)))[i];
    g.x += gb.x; g.y += gb.y; g.z += gb.z; g.w += gb.w;
    u.x += ub.x; u.y += ub.y; u.z += ub.z; u.w += ub.w;
  }
  union { _Float16 h4[4]; uint2 w; } o;
  o.h4[0] = (_Float16)(g.x / (1.f + __expf(-g.x)) * u.x);
  o.h4[1] = (_Float16)(g.y / (1.f + __expf(-g.y)) * u.y);
  o.h4[2] = (_Float16)(g.z / (1.f + __expf(-g.z)) * u.z);
  o.h4[3] = (_Float16)(g.w / (1.f + __expf(-g.w)) * u.w);
  ((uint2*)h)[i] = o.w;
}

// down-proj GEMM: grid = 64*dsplit
__global__ __launch_bounds__(256, 2) void k_gemm_down(
    const int* __restrict__ dc, const float* __restrict__ ds,
    const _Float16* __restrict__ h, float* __restrict__ part, int dsplit)
{
  __shared__ uint32_t lut[256];
  int tid = threadIdx.x;
  lut_fill(lut, tid);
  __syncthreads();

  int bx = blockIdx.x;
  int sp   = bx % dsplit;
  int nblk = bx / dsplit;

  int kch = MDIM / dsplit;
  int nt  = kch / 64;
  int nbase = nblk * 64;

  int lane = tid & 63, wid = tid >> 6;
  int r15 = lane & 15, q = lane >> 4;
  int nrow = nbase + wid * 16 + r15;

  const int*      crow = dc + (size_t)nrow * MDIM + (size_t)sp * kch + q * 8;
  const float*    srow = ds + (size_t)nrow * (MDIM / 64) + (size_t)sp * nt;
  const _Float16* arow = h + (size_t)sp * kch + (size_t)r15 * MDIM + q * 8;

  f32x4 acc[4];
#pragma unroll
  for (int t = 0; t < 4; ++t) acc[t] = (f32x4){0.f, 0.f, 0.f, 0.f};

  nf4_gemm_reg(crow, srow, arow, 16 * MDIM, nt, lut, acc);

  float* op = part + (size_t)sp * (TOKN * HD);
#pragma unroll
  for (int t = 0; t < 4; ++t)
#pragma unroll
    for (int rr = 0; rr < 4; ++rr) {
      int token = t * 16 + 4 * q + rr;
      op[(size_t)token * HD + nbase + wid * 16 + r15] = acc[t][rr];
    }
}

__global__ void k_reduce_out(const float* __restrict__ part,
                             float* __restrict__ out, int dsplit) {
  int i = blockIdx.x * blockDim.x + threadIdx.x;
  float4 a = ((const float4*)part)[i];
  for (int s = 1; s < dsplit; ++s) {
    float4 b = ((const float4*)(part + (size_t)s * (TOKN * HD)))[i];
    a.x += b.x; a.y += b.y; a.z += b.z; a.w += b.w;
  }
  ((float4*)out)[i] = a;
}

extern "C" void kernel_launch(void* const* d_in, const int* in_sizes, int n_in,
                              void* d_out, int out_size, void* d_ws, size_t ws_size,
                              hipStream_t stream) {
  (void)in_sizes; (void)n_in; (void)out_size; (void)ws_size;
  const float* x  = (const float*)d_in[0];
  const int*   gc = (const int*)d_in[1];
  const float* gs = (const float*)d_in[2];
  const int*   uc = (const int*)d_in[3];
  const float* us = (const float*)d_in[4];
  const int*   dc = (const int*)d_in[5];
  const float* ds = (const float*)d_in[6];
  float* out = (float*)d_out;

  const size_t XH_B  = (size_t)TOKN * HD * sizeof(_Float16);    // 512 KB
  const size_t H_B   = (size_t)TOKN * MDIM * sizeof(_Float16);  // 1.75 MB
  const size_t GU1_B = (size_t)TOKN * MDIM * sizeof(float);     // 3.5 MB per split per mat
  const size_t FIX_B = XH_B + H_B;

  // nt % 4 == 0: gsplit in {1,2,4,8}; dsplit such that (14336/64)/dsplit %4==0 -> {1,2,4,8,14,28}
  const int gsplit = 2, dsplit = 8;   // 16.3 MB total; ws >= 30 MB observed

  char* w = (char*)d_ws;
  _Float16* xh    = (_Float16*)w;
  _Float16* hbuf  = (_Float16*)(w + XH_B);
  float*    gpart = (float*)(w + FIX_B);
  float*    upart = (float*)(w + FIX_B + (size_t)gsplit * GU1_B);
  float*    dpart = (float*)(w + FIX_B);   // overlays g/u parts (dead by then)

  k_cvt_x        <<<256, 256, 0, stream>>>(x, xh);
  k_gemm_gu      <<<448 * gsplit, 256, 0, stream>>>(gc, gs, uc, us, xh, gpart, upart, gsplit);
  k_reduce_swiglu<<<896, 256, 0, stream>>>(gpart, upart, hbuf, gsplit);
  k_gemm_down    <<<64 * dsplit, 256, 0, stream>>>(dc, ds, hbuf, dpart, dsplit);
  k_reduce_out   <<<256, 256, 0, stream>>>(dpart, out, dsplit);
}